// Round 10
// baseline (334.233 us; speedup 1.0000x reference)
//
#include <hip/hip_runtime.h>
#include <cstddef>

#define HU    4096
#define NBLK  256
#define NTHR  512
#define MAXIT 100
#define TOL2  1e-7f

// workspace layout (float offsets)
#define WS_STS  0
#define WS_DINV 4096
#define WS_R0   8192
#define WS_U0   12288
#define WS_W    16384                    // DOUBLE buffer: 2 x 4096 (parity k&1)
#define WS_BAR  24576                    // 2 x 256 tagged 8B slots (parity gen&1)
#define WS_FLG  (WS_BAR + 1024)          // 8 x 64B flag lines: (gen<<32)|dk bits
#define WS_END  (WS_FLG + 128)

typedef _Float16 half4v __attribute__((ext_vector_type(4)));

// raw-approx transcendentals — avoids hipcc's IEEE div/sqrt expansion on the
// Jacobi critical path. c^2+s^2 = 1 +- 3e-7 per rotation: drift ~1e-4, safe.
__device__ __forceinline__ float fastrcp(float x) {
  float r; asm("v_rcp_f32 %0, %1" : "=v"(r) : "v"(x)); return r;
}
__device__ __forceinline__ float fastsqrt(float x) {
  float r; asm("v_sqrt_f32 %0, %1" : "=v"(r) : "v"(x)); return r;
}
__device__ __forceinline__ float fastrsq(float x) {
  float r; asm("v_rsq_f32 %0, %1" : "=v"(r) : "v"(x)); return r;
}

__device__ __forceinline__ float waveReduce(float v) {
#pragma unroll
  for (int off = 32; off > 0; off >>= 1) v += __shfl_xor(v, off, 64);
  return v;
}

// Block-wide sum over 8 waves; returns same value in all threads.
__device__ __forceinline__ float blockSum(float v, float* red) {
  v = waveReduce(v);
  if ((threadIdx.x & 63) == 0) red[threadIdx.x >> 6] = v;
  __syncthreads();
  float s = 0.f;
#pragma unroll
  for (int i = 0; i < 8; ++i) s += red[i];
  __syncthreads();
  return s;
}

// ---------------------------------------------------------------------------
// Grid barrier + global dot-product, master-poll topology:
//  - every block release-stores (gen<<32 | bits(block_delta)) into its own
//    tagged 8B slot (parity gen&1; no atomic RMW anywhere);
//  - ONLY block 0's wave 0 polls the 256 slots (4 loads/lane); on success the
//    registers already hold all deltas -> dk = waveReduce, no extra gather;
//  - release fans out to 8 XCD-spread flag lines carrying (gen<<32 | dk bits);
//    spinners read ONE 8B word to get both barrier release and dk.
// ---------------------------------------------------------------------------
__device__ __forceinline__ float gsync_dk(unsigned long long* slots,
                                          unsigned long long* flgq,
                                          unsigned gen, float* red) {
  __syncthreads();                       // red[] complete + block's global writes done
  const int tid = threadIdx.x, lane = tid & 63, b = blockIdx.x;
  unsigned long long* arr = slots + (gen & 1) * 256;
  if (b == 0) {
    if (tid < 64) {
      if (lane == 0) {
        float s = 0.f;
#pragma unroll
        for (int i = 0; i < 8; ++i) s += red[i];
        __threadfence();                 // release all prior global writes
        __hip_atomic_store(&arr[0],
                           ((unsigned long long)gen << 32) | __float_as_uint(s),
                           __ATOMIC_RELEASE, __HIP_MEMORY_SCOPE_AGENT);
      }
      float dsum;
      for (;;) {
        const unsigned long long v0 = __hip_atomic_load(&arr[lane],
                                        __ATOMIC_RELAXED, __HIP_MEMORY_SCOPE_AGENT);
        const unsigned long long v1 = __hip_atomic_load(&arr[lane + 64],
                                        __ATOMIC_RELAXED, __HIP_MEMORY_SCOPE_AGENT);
        const unsigned long long v2 = __hip_atomic_load(&arr[lane + 128],
                                        __ATOMIC_RELAXED, __HIP_MEMORY_SCOPE_AGENT);
        const unsigned long long v3 = __hip_atomic_load(&arr[lane + 192],
                                        __ATOMIC_RELAXED, __HIP_MEMORY_SCOPE_AGENT);
        const bool ok = ((unsigned)(v0 >> 32) >= gen) && ((unsigned)(v1 >> 32) >= gen)
                     && ((unsigned)(v2 >> 32) >= gen) && ((unsigned)(v3 >> 32) >= gen);
        if (__all(ok)) {
          dsum = __uint_as_float((unsigned)v0) + __uint_as_float((unsigned)v1)
               + __uint_as_float((unsigned)v2) + __uint_as_float((unsigned)v3);
          break;
        }
        __builtin_amdgcn_s_sleep(1);
      }
      const float dk = waveReduce(dsum);
      __threadfence();                   // acquire: see all blocks' writes
      if (lane < 8)
        __hip_atomic_store(&flgq[lane * 8],
                           ((unsigned long long)gen << 32) | __float_as_uint(dk),
                           __ATOMIC_RELEASE, __HIP_MEMORY_SCOPE_AGENT);
      if (lane == 0) red[0] = dk;
    }
  } else if (tid == 0) {
    float s = 0.f;
#pragma unroll
    for (int i = 0; i < 8; ++i) s += red[i];
    __threadfence();                     // release all prior global writes
    __hip_atomic_store(&arr[b],
                       ((unsigned long long)gen << 32) | __float_as_uint(s),
                       __ATOMIC_RELEASE, __HIP_MEMORY_SCOPE_AGENT);
    unsigned long long* fq = flgq + (b & 7) * 8;
    unsigned long long f;
    for (;;) {
      f = __hip_atomic_load(fq, __ATOMIC_RELAXED, __HIP_MEMORY_SCOPE_AGENT);
      if ((unsigned)(f >> 32) >= gen) break;
      __builtin_amdgcn_s_sleep(1);
    }
    __threadfence();                     // acquire: see all blocks' writes
    red[0] = __uint_as_float((unsigned)f);
  }
  __syncthreads();
  const float dk = red[0];
  __syncthreads();                       // guard red[0] before blockSum reuse
  return dk;
}

#define SWP 6          // max Jacobi sweeps
#define S_W 68         // column stride in floats (16B-aligned, bank-spreading)

// sum across each 16-lane group via DPP row_ror (VALU pipe, not LDS unit)
__device__ __forceinline__ float red16(float x) {
  int t;
  t = __builtin_amdgcn_update_dpp(0, __float_as_int(x), 0x128, 0xF, 0xF, false); // row_ror:8
  x += __int_as_float(t);
  t = __builtin_amdgcn_update_dpp(0, __float_as_int(x), 0x124, 0xF, 0xF, false); // row_ror:4
  x += __int_as_float(t);
  t = __builtin_amdgcn_update_dpp(0, __float_as_int(x), 0x122, 0xF, 0xF, false); // row_ror:2
  x += __int_as_float(t);
  t = __builtin_amdgcn_update_dpp(0, __float_as_int(x), 0x121, 0xF, 0xF, false); // row_ror:1
  x += __int_as_float(t);
  return x;
}

// GF(8) multiply, poly x^3 + x + 1
__device__ __forceinline__ int gf8mul(int a, int b) {
  int p = 0;
  if (b & 1) p ^= a;
  if (b & 2) p ^= (a << 1);
  if (b & 4) p ^= (a << 2);
  if (p & 16) p ^= 22;                   // x^4 -> x^2 + x
  if (p & 8)  p ^= 11;                   // x^3 -> x + 1
  return p;
}

// ---------------------------------------------------------------------------
// FUSED kernel: CG solve (all 256 blocks, cooperative) then SVT (block 0 only,
// one-sided V-less Jacobi, AG(2,8) schedule, norm-carrying, UNROLLED
// tournament with compile-time schedule constants + 3-transcendental
// rotation params (rsq -> sqrt -> rcp chain, stable for small angles).
// ---------------------------------------------------------------------------
__global__ void __launch_bounds__(NTHR, 1)
fused_kernel(const float* __restrict__ x_in, const float* __restrict__ L_in,
             const int* __restrict__ mask, const float* __restrict__ D,
             const float* __restrict__ thP, const float* __restrict__ S,
             const float* __restrict__ l1p, const float* __restrict__ l2p,
             const float* __restrict__ rhop, const float* __restrict__ vp,
             const float* __restrict__ cgp, const float* __restrict__ netap,
             float* __restrict__ ws, float* __restrict__ out)
{
  __shared__ __align__(16) float u_l[HU];          // 16 KB (block-shared u)
  __shared__ __align__(16) char pool[128 * 1024];  // CG: fp16 D rows | SVT: Wl/Yr/T1/Wr
  __shared__ float red[8];
  __shared__ float g_s[64];
  __shared__ float nrm[64];                        // carried column norms (SVT)
  unsigned long long* slots = (unsigned long long*)(ws + WS_BAR);
  unsigned long long* flgq  = (unsigned long long*)(ws + WS_FLG);
  const float* sts = ws + WS_STS;
  const float lam1 = *l1p, lam2 = *l2p, rho = *rhop;
  const int tid = threadIdx.x, b = blockIdx.x;
  const int wv = tid >> 6, lane = tid & 63;
  unsigned gen = 0;

  // ---- init (blocks 0..7 write global sts/dinv/r0/u0) ----
  const int gtid = b * NTHR + tid;
  if (gtid < HU) {
    const int a = gtid >> 6, c = gtid & 63;
    float acc = 0.f, sdiag = 0.f;
    for (int h = 0; h < 64; ++h) {
      const float sa = S[h * 64 + a], sc = S[h * 64 + c];
      acc = fmaf(sa, sc, acc);
      sdiag = fmaf(sc, sc, sdiag);
    }
    ws[WS_STS + gtid] = acc;
    const float q = mask[gtid] ? 1.f : 0.f;
    const float diag = q + rho + lam1 * D[(size_t)gtid * (HU + 1)] + lam2 * sdiag;
    const float bb = rho * (L_in[gtid] - thP[gtid]) + (mask[gtid] ? x_in[gtid] : 0.f);
    const float di = 1.f / diag;
    ws[WS_DINV + gtid] = di;
    ws[WS_R0 + gtid] = bb;
    ws[WS_U0 + gtid] = bb * di;
  }

  // ---- stage this block's 16 D rows into LDS as fp16 (one-time 64 MB read) ----
  {
    const float4* __restrict__ Dg = (const float4*)(D + (size_t)b * 16 * HU);
    half4v* __restrict__ Dh4 = (half4v*)pool;
    for (int o = tid; o < 16 * HU / 4; o += NTHR) {
      const float4 dv = Dg[o];
      half4v h;
      h[0] = (_Float16)dv.x; h[1] = (_Float16)dv.y;
      h[2] = (_Float16)dv.z; h[3] = (_Float16)dv.w;
      Dh4[o] = h;
    }
  }
  if (tid < 8) red[tid] = 0.f;           // init barrier carries no delta
  gsync_dk(slots, flgq, ++gen, red);

  // ---- every block mirrors r0,u0,dinv; r/s/dinv are thread-private -> regs ----
  float r_reg[8], s_reg[8], dinv_reg[8];
  float acc0 = 0.f;
#pragma unroll
  for (int m = 0; m < 8; ++m) {
    const int i = tid + m * NTHR;
    const float rv = ws[WS_R0 + i], uv = ws[WS_U0 + i];
    r_reg[m] = rv; u_l[i] = uv; dinv_reg[m] = ws[WS_DINV + i];
    s_reg[m] = 0.f;
  }
  __syncthreads();                       // u_l visible block-wide
#pragma unroll
  for (int m = 0; m < 8; ++m) acc0 = fmaf(r_reg[m], u_l[tid + m * NTHR], acc0);
  const float gamma0 = blockSum(acc0, red);

  // x/p state only matters on block 0 (SVT consumes x from its registers)
  float p_arr[8], x_arr[8];
#pragma unroll
  for (int m = 0; m < 8; ++m) { p_arr[m] = 0.f; x_arr[m] = 0.f; }

  const int row0 = b * 16 + wv * 2;      // 2 rows per wave
  const int iq = row0 >> 6, j0 = row0 & 63;
  const float4* __restrict__ u4 = (const float4*)u_l;
  const float m0 = mask[row0] ? 1.f : 0.f;
  const float m1 = mask[row0 + 1] ? 1.f : 0.f;
  const float sts0 = sts[j0 * 64 + lane];
  const float sts1 = sts[j0 * 64 + 64 + lane];
  // exact-diagonal correction: fp16(D_ii) error folded back in fp32
  const float dex0 = D[(size_t)row0 * (HU + 1)];
  const float dex1 = D[(size_t)(row0 + 1) * (HU + 1)];
  const float diagf0 = m0 + rho + lam1 * (dex0 - (float)(_Float16)dex0);
  const float diagf1 = m1 + rho + lam1 * (dex1 - (float)(_Float16)dex1);
  const half4v* __restrict__ H0 = (const half4v*)((_Float16*)pool + (size_t)(wv * 2) * HU);
  const half4v* __restrict__ H1 = H0 + (HU / 4);

  float gamma = gamma0, gamma_prev = 1.f, alpha_prev = 1.f;
  for (int k = 0; k < MAXIT; ++k) {
    // ---- matvec: w = A u (u + fp16 D both from LDS) ----
    float* __restrict__ wbuf = ws + WS_W + (k & 1) * HU;
    {
      float acc_a = 0.f, acc_b = 0.f;
#pragma unroll
      for (int it = 0; it < 16; ++it) {
        const float4 uu = u4[it * 64 + lane];
        const half4v d0 = H0[it * 64 + lane];
        const half4v d1 = H1[it * 64 + lane];
        acc_a = fmaf((float)d0[0], uu.x, acc_a); acc_a = fmaf((float)d0[1], uu.y, acc_a);
        acc_a = fmaf((float)d0[2], uu.z, acc_a); acc_a = fmaf((float)d0[3], uu.w, acc_a);
        acc_b = fmaf((float)d1[0], uu.x, acc_b); acc_b = fmaf((float)d1[1], uu.y, acc_b);
        acc_b = fmaf((float)d1[2], uu.z, acc_b); acc_b = fmaf((float)d1[3], uu.w, acc_b);
      }
      const float us = u_l[iq * 64 + lane];
      float t0 = fmaf(lam1, acc_a, lam2 * (sts0 * us));
      float t1 = fmaf(lam1, acc_b, lam2 * (sts1 * us));
      t0 = waveReduce(t0);
      t1 = waveReduce(t1);
      const float u0v = u_l[row0], u1v = u_l[row0 + 1];
      const float w0 = t0 + diagf0 * u0v;
      const float w1 = t1 + diagf1 * u1v;
      if (lane == 0) {
        wbuf[row0] = w0;
        wbuf[row0 + 1] = w1;
        red[wv] = fmaf(w0, u0v, w1 * u1v);   // this block's delta partial
      }
    }
    // ---- master-poll barrier; dk piggybacked on the release flag ----
    const float dk = gsync_dk(slots, flgq, ++gen, red);

    // stage wbuf reads early (independent of the scalar math below)
    float wv_r[8];
#pragma unroll
    for (int m = 0; m < 8; ++m) wv_r[m] = wbuf[tid + m * NTHR];

    // ---- scalars (identical in every block: dk broadcast from master) ----
    const float beta  = (k == 0) ? 0.f : gamma * fastrcp(gamma_prev);
    const float denom = (k == 0) ? dk  : (dk - beta * gamma * fastrcp(alpha_prev));
    const float alpha = gamma * fastrcp(denom);

    // ---- redundant local update (p/x use uold = u_k read BEFORE overwrite) ----
    float acc = 0.f;
#pragma unroll
    for (int m = 0; m < 8; ++m) {
      const int i = tid + m * NTHR;
      const float uold = u_l[i];                       // u_k
      const float sv = (k == 0) ? wv_r[m] : fmaf(beta, s_reg[m], wv_r[m]);
      s_reg[m] = sv;
      const float rv = fmaf(-alpha, sv, r_reg[m]);
      r_reg[m] = rv;
      const float uv = rv * dinv_reg[m];               // u_{k+1}
      u_l[i] = uv;
      acc = fmaf(rv, uv, acc);
      if (b == 0) {                                    // only block 0 needs x
        const float pk = (k == 0) ? uold : fmaf(beta, p_arr[m], uold);
        p_arr[m] = pk;
        x_arr[m] = fmaf(alpha, pk, x_arr[m]);
      }
    }
    const float gnext = blockSum(acc, red);  // barrier also publishes u_l

    gamma_prev = gamma;
    alpha_prev = alpha;
    gamma = gnext;
    if (!(gnext > TOL2 * gamma0)) break; // uniform grid-wide (identical local math)
  }

  if (b != 0) return;                    // SVT runs on block 0 only; x in regs

  // =========================================================================
  // SVT: one-sided V-less Jacobi on Y = X + th_P.  Ltmp = W diag(g/s^2) W^T Y.
  // AG(2,8): 9 meta-rounds/sweep, 7-round unrolled in-octet tournament.
  // =========================================================================
  float* Wl = (float*)pool;              // W col-major: Wl[c*S_W + r]
  float* Yr = Wl + 64 * S_W;             // pristine Y ROW-major
  float* T1 = Yr + 64 * S_W;             // T1[k][j] = (W^T Y)[k][j]
  float* Wr = T1 + 64 * S_W;             // Wr[i][k] = W[i][k]*gg[k]
  __syncthreads();

  float t0acc = 0.f;
#pragma unroll
  for (int mm = 0; mm < 8; ++mm) {
    const int i = tid + mm * NTHR;
    const int rr = i >> 6, cc = i & 63;
    const float y = x_arr[mm] + thP[i];
    Wl[cc * S_W + rr] = y;
    Yr[rr * S_W + cc] = y;
    t0acc = fmaf(y, y, t0acc);
  }
  const float T0 = blockSum(t0acc, red);     // barrier: Wl now visible
  // initial column norms
  if (tid < 64) {
    const float4* wc = (const float4*)(Wl + tid * S_W);
    float nn = 0.f;
#pragma unroll
    for (int i2 = 0; i2 < 16; ++i2) {
      const float4 u = wc[i2];
      nn = fmaf(u.x, u.x, fmaf(u.y, u.y, fmaf(u.z, u.z, fmaf(u.w, u.w, nn))));
    }
    nrm[tid] = nn;
  }
  __syncthreads();
  // exit when true off_F^2 <= 1e-11*T0^2 (offacc is x16: every lane counts)
  const float thr = 1.6e-10f * T0 * T0;

  const int team = lane >> 4;                // pair-team within wave, 0..3
  const int sub  = lane & 15;                // slice within column (4 floats)

  for (int sweep = 0; sweep < SWP; ++sweep) {
    float offacc = 0.f;
    for (int mr = 0; mr < 9; ++mr) {         // NOT unrolled (code size)
      // this wave's octet: line wv of parallel class mr in AG(2,8)
      int cols[8];
#pragma unroll
      for (int j = 0; j < 8; ++j)
        cols[j] = (mr == 8) ? (8 * wv + j) : (8 * j + (gf8mul(mr, j) ^ wv));
      // 7-round tournament, UNROLLED: schedule indices are compile-time,
      // so column selects are 3 cndmasks and addresses are ready up front.
#pragma unroll
      for (int r = 0; r < 7; ++r) {
        const int A1 = (r + 1) % 7, A2 = (r + 2) % 7, A3 = (r + 3) % 7;
        const int B0 = r % 7, B1 = (r + 6) % 7, B2 = (r + 5) % 7, B3 = (r + 4) % 7;
        const int cp = (team == 0) ? cols[7] : (team == 1) ? cols[A1]
                     : (team == 2) ? cols[A2] : cols[A3];
        const int cq = (team == 0) ? cols[B0] : (team == 1) ? cols[B1]
                     : (team == 2) ? cols[B2] : cols[B3];
        float4* wp = (float4*)(Wl + cp * S_W) + sub;
        float4* wq = (float4*)(Wl + cq * S_W) + sub;
        const float4 a = *wp, bb = *wq;
        const float dpp = nrm[cp];             // carried (LDS broadcast)
        const float dqq = nrm[cq];
        float dpq = fmaf(a.x, bb.x, fmaf(a.y, bb.y, fmaf(a.z, bb.z, a.w * bb.w)));
        dpq = red16(dpq);                      // the ONLY reduce per round
        offacc = fmaf(dpq, dpq, offacc);
        // team-uniform skip of converged pairs
        if (dpq * dpq > 1e-14f * dpp * dqq) {
          // 3-transcendental rotation params (chain: rsq -> sqrt -> rcp):
          // h = sqrt(d^2 + (2dpq)^2); cos2t = |d|/h; c = sqrt((1+cos2t)/2);
          // s = sign(d) * 2dpq/h / (2c)   (sin2t computed stably)
          const float d  = dqq - dpp;
          const float u2 = 2.f * dpq;
          const float z  = fmaf(d, d, u2 * u2);
          const float ih = fastrsq(z);
          const float c1 = fastsqrt(fmaf(0.5f * fabsf(d), ih, 0.5f));
          const float sg = (d >= 0.f) ? 0.5f : -0.5f;
          const float s1 = sg * u2 * ih * fastrcp(c1);
          float4 na, nb;
          na.x = c1 * a.x - s1 * bb.x;  nb.x = s1 * a.x + c1 * bb.x;
          na.y = c1 * a.y - s1 * bb.y;  nb.y = s1 * a.y + c1 * bb.y;
          na.z = c1 * a.z - s1 * bb.z;  nb.z = s1 * a.z + c1 * bb.z;
          na.w = c1 * a.w - s1 * bb.w;  nb.w = s1 * a.w + c1 * bb.w;
          *wp = na; *wq = nb;
          if (sub == 0) {                      // analytic norm update
            const float cc2 = c1 * c1, ss2 = s1 * s1, cs2 = 2.f * c1 * s1;
            nrm[cp] = cc2 * dpp - cs2 * dpq + ss2 * dqq;
            nrm[cq] = ss2 * dpp + cs2 * dpq + cc2 * dqq;
          }
        }
      }
      __syncthreads();                   // octet handoff between meta-rounds
    }
    // certificate on PRE-sweep state; post-sweep off is quadratically smaller.
    const float tot = blockSum(offacc, red);
    if (tot < thr) break;
  }

  // ---- sigma from column norms (FRESH, not carried); gg = relu(s-tau)/s^3 ----
  if (tid < 64) {
    const float4* wc = (const float4*)(Wl + tid * S_W);
    float nn = 0.f;
#pragma unroll
    for (int i2 = 0; i2 < 16; ++i2) {
      const float4 u = wc[i2];
      nn = fmaf(u.x, u.x, fmaf(u.y, u.y, fmaf(u.z, u.z, fmaf(u.w, u.w, nn))));
    }
    const float sv = sqrtf(nn);
    const float tau = (*cgp) / (1.f + expf(-(*vp)));
    g_s[tid] = (sv > tau) ? (sv - tau) / (sv * nn) : 0.f;   // (s-tau)/s^3
  }
  __syncthreads();

  const int j = tid & 63;
  const int ib = tid >> 6;

  // ---- T1[k][j] = sum_i W[i][k] * Y[i][j] ----
#pragma unroll
  for (int mm = 0; mm < 8; ++mm) {
    const int k = ib + 8 * mm;                        // uniform per wave
    const float4* wcol = (const float4*)(Wl + k * S_W);
    float acc = 0.f;
#pragma unroll
    for (int i4 = 0; i4 < 16; ++i4) {
      const float4 wvv = wcol[i4];                    // LDS broadcast
      acc = fmaf(wvv.x, Yr[(4 * i4 + 0) * S_W + j], acc);
      acc = fmaf(wvv.y, Yr[(4 * i4 + 1) * S_W + j], acc);
      acc = fmaf(wvv.z, Yr[(4 * i4 + 2) * S_W + j], acc);
      acc = fmaf(wvv.w, Yr[(4 * i4 + 3) * S_W + j], acc);
    }
    T1[k * S_W + j] = acc;
  }
  // ---- Wr[i][k] = W[i][k] * gg[k] (transpose with gain fold) ----
  for (int o = tid; o < 4096; o += 512) {
    const int i2 = o >> 6, kk = o & 63;
    Wr[i2 * S_W + kk] = Wl[kk * S_W + i2] * g_s[kk];
  }
  __syncthreads();

  // ---- Ltmp = Wr * T1; Ptmp = thP + neta (X - Ltmp)  (X from registers) ----
  const float neta = *netap;
#pragma unroll
  for (int mm = 0; mm < 8; ++mm) {
    const int i2 = ib + 8 * mm;                       // uniform per wave
    const float4* wrow = (const float4*)(Wr + i2 * S_W);
    float acc = 0.f;
#pragma unroll
    for (int k4 = 0; k4 < 16; ++k4) {
      const float4 wvv = wrow[k4];                    // LDS broadcast
      acc = fmaf(wvv.x, T1[(4 * k4 + 0) * S_W + j], acc);
      acc = fmaf(wvv.y, T1[(4 * k4 + 1) * S_W + j], acc);
      acc = fmaf(wvv.z, T1[(4 * k4 + 2) * S_W + j], acc);
      acc = fmaf(wvv.w, T1[(4 * k4 + 3) * S_W + j], acc);
    }
    const int o = i2 * 64 + j;                        // == tid + mm*512
    out[o] = acc;                                     // Ltmp
    out[4096 + o] = thP[o] + neta * (x_arr[mm] - acc);// Ptmp
  }
}

extern "C" void kernel_launch(void* const* d_in, const int* in_sizes, int n_in,
                              void* d_out, int out_size, void* d_ws, size_t ws_size,
                              hipStream_t stream)
{
  const float* x_in  = (const float*)d_in[0];
  const float* L_in  = (const float*)d_in[1];
  const int*   mask  = (const int*)d_in[2];
  const float* D     = (const float*)d_in[3];
  const float* thP   = (const float*)d_in[4];
  const float* vp    = (const float*)d_in[5];
  const float* cgp   = (const float*)d_in[6];
  const float* netap = (const float*)d_in[7];
  const float* l1p   = (const float*)d_in[8];
  const float* l2p   = (const float*)d_in[9];
  const float* rhop  = (const float*)d_in[10];
  const float* S     = (const float*)d_in[11];
  float* ws  = (float*)d_ws;
  float* out = (float*)d_out;

  // zero the tagged slots + flag lines (re-runs on every graph replay)
  hipMemsetAsync(ws + WS_BAR, 0, (WS_END - WS_BAR) * sizeof(float), stream);

  void* args[] = { (void*)&x_in, (void*)&L_in, (void*)&mask, (void*)&D, (void*)&thP,
                   (void*)&S, (void*)&l1p, (void*)&l2p, (void*)&rhop,
                   (void*)&vp, (void*)&cgp, (void*)&netap, (void*)&ws, (void*)&out };
  hipLaunchCooperativeKernel((void*)fused_kernel, dim3(NBLK), dim3(NTHR),
                             args, 0, stream);
}

// Round 11
// 316.042 us; speedup vs baseline: 1.0576x; 1.0576x over previous
//
#include <hip/hip_runtime.h>
#include <cstddef>

#define HU    4096
#define NBLK  256
#define NTHR  512
#define MAXIT 100
#define TOL2  1e-7f

// workspace layout (float offsets)
#define WS_STS  0
#define WS_DINV 4096
#define WS_R0   8192
#define WS_U0   12288
#define WS_W    16384                    // DOUBLE buffer: 2 x 4096 (parity k&1)
#define WS_BAR  24576                    // 2 x 256 tagged 8B slots (parity gen&1)
#define WS_FLG  (WS_BAR + 1024)          // 8 x 64B flag lines: (gen<<32)|dk bits
#define WS_END  (WS_FLG + 128)

typedef _Float16 half4v __attribute__((ext_vector_type(4)));

// raw-approx transcendentals — avoids hipcc's IEEE div/sqrt expansion on the
// Jacobi critical path. c^2+s^2 = 1 +- 3e-7 per rotation: drift ~1e-4, safe.
__device__ __forceinline__ float fastrcp(float x) {
  float r; asm("v_rcp_f32 %0, %1" : "=v"(r) : "v"(x)); return r;
}
__device__ __forceinline__ float fastsqrt(float x) {
  float r; asm("v_sqrt_f32 %0, %1" : "=v"(r) : "v"(x)); return r;
}
__device__ __forceinline__ float fastrsq(float x) {
  float r; asm("v_rsq_f32 %0, %1" : "=v"(r) : "v"(x)); return r;
}

__device__ __forceinline__ float waveReduce(float v) {
#pragma unroll
  for (int off = 32; off > 0; off >>= 1) v += __shfl_xor(v, off, 64);
  return v;
}

// Block-wide sum over 8 waves; returns same value in all threads.
__device__ __forceinline__ float blockSum(float v, float* red) {
  v = waveReduce(v);
  if ((threadIdx.x & 63) == 0) red[threadIdx.x >> 6] = v;
  __syncthreads();
  float s = 0.f;
#pragma unroll
  for (int i = 0; i < 8; ++i) s += red[i];
  __syncthreads();
  return s;
}

// ---------------------------------------------------------------------------
// Grid barrier + global dot-product, master-poll topology:
//  - every block release-stores (gen<<32 | bits(block_delta)) into its own
//    tagged 8B slot (parity gen&1; no atomic RMW anywhere);
//  - ONLY block 0's wave 0 polls the 256 slots (4 loads/lane); on success the
//    registers already hold all deltas -> dk = waveReduce, no extra gather;
//  - release fans out to 8 XCD-spread flag lines carrying (gen<<32 | dk bits);
//    spinners read ONE 8B word to get both barrier release and dk.
// dk comes back via a DEDICATED LDS slot (dks) so no trailing guard barrier
// is needed: the next write to dks is ordered by the next call's entry
// __syncthreads().
// ---------------------------------------------------------------------------
__device__ __forceinline__ float gsync_dk(unsigned long long* slots,
                                          unsigned long long* flgq,
                                          unsigned gen, float* red, float* dks) {
  __syncthreads();                       // red[] complete + block's global writes done
  const int tid = threadIdx.x, lane = tid & 63, b = blockIdx.x;
  unsigned long long* arr = slots + (gen & 1) * 256;
  if (b == 0) {
    if (tid < 64) {
      if (lane == 0) {
        float s = 0.f;
#pragma unroll
        for (int i = 0; i < 8; ++i) s += red[i];
        __threadfence();                 // release all prior global writes
        __hip_atomic_store(&arr[0],
                           ((unsigned long long)gen << 32) | __float_as_uint(s),
                           __ATOMIC_RELEASE, __HIP_MEMORY_SCOPE_AGENT);
      }
      float dsum;
      for (;;) {
        const unsigned long long v0 = __hip_atomic_load(&arr[lane],
                                        __ATOMIC_RELAXED, __HIP_MEMORY_SCOPE_AGENT);
        const unsigned long long v1 = __hip_atomic_load(&arr[lane + 64],
                                        __ATOMIC_RELAXED, __HIP_MEMORY_SCOPE_AGENT);
        const unsigned long long v2 = __hip_atomic_load(&arr[lane + 128],
                                        __ATOMIC_RELAXED, __HIP_MEMORY_SCOPE_AGENT);
        const unsigned long long v3 = __hip_atomic_load(&arr[lane + 192],
                                        __ATOMIC_RELAXED, __HIP_MEMORY_SCOPE_AGENT);
        const bool ok = ((unsigned)(v0 >> 32) >= gen) && ((unsigned)(v1 >> 32) >= gen)
                     && ((unsigned)(v2 >> 32) >= gen) && ((unsigned)(v3 >> 32) >= gen);
        if (__all(ok)) {
          dsum = __uint_as_float((unsigned)v0) + __uint_as_float((unsigned)v1)
               + __uint_as_float((unsigned)v2) + __uint_as_float((unsigned)v3);
          break;
        }
        __builtin_amdgcn_s_sleep(1);
      }
      const float dk = waveReduce(dsum);
      __threadfence();                   // acquire: see all blocks' writes
      if (lane < 8)
        __hip_atomic_store(&flgq[lane * 8],
                           ((unsigned long long)gen << 32) | __float_as_uint(dk),
                           __ATOMIC_RELEASE, __HIP_MEMORY_SCOPE_AGENT);
      if (lane == 0) dks[0] = dk;
    }
  } else if (tid == 0) {
    float s = 0.f;
#pragma unroll
    for (int i = 0; i < 8; ++i) s += red[i];
    __threadfence();                     // release all prior global writes
    __hip_atomic_store(&arr[b],
                       ((unsigned long long)gen << 32) | __float_as_uint(s),
                       __ATOMIC_RELEASE, __HIP_MEMORY_SCOPE_AGENT);
    unsigned long long* fq = flgq + (b & 7) * 8;
    unsigned long long f;
    for (;;) {
      f = __hip_atomic_load(fq, __ATOMIC_RELAXED, __HIP_MEMORY_SCOPE_AGENT);
      if ((unsigned)(f >> 32) >= gen) break;
      __builtin_amdgcn_s_sleep(1);
    }
    __threadfence();                     // acquire: see all blocks' writes
    dks[0] = __uint_as_float((unsigned)f);
  }
  __syncthreads();
  return dks[0];                         // no guard needed: next write to dks
                                         // is after the next call's entry sync
}

#define SWP 6          // max Jacobi sweeps
#define S_W 68         // column stride in floats (16B-aligned, bank-spreading)

// sum across each 16-lane group via DPP row_ror (VALU pipe, not LDS unit)
__device__ __forceinline__ float red16(float x) {
  int t;
  t = __builtin_amdgcn_update_dpp(0, __float_as_int(x), 0x128, 0xF, 0xF, false); // row_ror:8
  x += __int_as_float(t);
  t = __builtin_amdgcn_update_dpp(0, __float_as_int(x), 0x124, 0xF, 0xF, false); // row_ror:4
  x += __int_as_float(t);
  t = __builtin_amdgcn_update_dpp(0, __float_as_int(x), 0x122, 0xF, 0xF, false); // row_ror:2
  x += __int_as_float(t);
  t = __builtin_amdgcn_update_dpp(0, __float_as_int(x), 0x121, 0xF, 0xF, false); // row_ror:1
  x += __int_as_float(t);
  return x;
}

// GF(8) multiply, poly x^3 + x + 1
__device__ __forceinline__ int gf8mul(int a, int b) {
  int p = 0;
  if (b & 1) p ^= a;
  if (b & 2) p ^= (a << 1);
  if (b & 4) p ^= (a << 2);
  if (p & 16) p ^= 22;                   // x^4 -> x^2 + x
  if (p & 8)  p ^= 11;                   // x^3 -> x + 1
  return p;
}

// runtime-index select from an 8-entry register array (cndmask chain, no scratch)
__device__ __forceinline__ int sel8(const int c[8], int i) {
  int r = c[0];
  r = (i == 1) ? c[1] : r;
  r = (i == 2) ? c[2] : r;
  r = (i == 3) ? c[3] : r;
  r = (i == 4) ? c[4] : r;
  r = (i == 5) ? c[5] : r;
  r = (i == 6) ? c[6] : r;
  r = (i == 7) ? c[7] : r;
  return r;
}

// ---------------------------------------------------------------------------
// FUSED kernel: CG solve (all 256 blocks, cooperative) then SVT (block 0 only,
// one-sided V-less Jacobi, AG(2,8) schedule — mr loop UNROLLED so gf8mul
// constant-folds — norm-carrying inner loop, 3-transcendental rotation params.
// ---------------------------------------------------------------------------
__global__ void __launch_bounds__(NTHR, 1)
fused_kernel(const float* __restrict__ x_in, const float* __restrict__ L_in,
             const int* __restrict__ mask, const float* __restrict__ D,
             const float* __restrict__ thP, const float* __restrict__ S,
             const float* __restrict__ l1p, const float* __restrict__ l2p,
             const float* __restrict__ rhop, const float* __restrict__ vp,
             const float* __restrict__ cgp, const float* __restrict__ netap,
             float* __restrict__ ws, float* __restrict__ out)
{
  __shared__ __align__(16) float u_l[HU];          // 16 KB (block-shared u)
  __shared__ __align__(16) char pool[128 * 1024];  // CG: fp16 D rows | SVT: Wl/Yr/T1/Wr
  __shared__ float red[8];
  __shared__ float dks[1];                         // dk broadcast slot
  __shared__ float g_s[64];
  __shared__ float nrm[64];                        // carried column norms (SVT)
  unsigned long long* slots = (unsigned long long*)(ws + WS_BAR);
  unsigned long long* flgq  = (unsigned long long*)(ws + WS_FLG);
  const float* sts = ws + WS_STS;
  const float lam1 = *l1p, lam2 = *l2p, rho = *rhop;
  const int tid = threadIdx.x, b = blockIdx.x;
  const int wv = tid >> 6, lane = tid & 63;
  unsigned gen = 0;

  // ---- init (blocks 0..7 write global sts/dinv/r0/u0) ----
  const int gtid = b * NTHR + tid;
  if (gtid < HU) {
    const int a = gtid >> 6, c = gtid & 63;
    float acc = 0.f, sdiag = 0.f;
    for (int h = 0; h < 64; ++h) {
      const float sa = S[h * 64 + a], sc = S[h * 64 + c];
      acc = fmaf(sa, sc, acc);
      sdiag = fmaf(sc, sc, sdiag);
    }
    ws[WS_STS + gtid] = acc;
    const float q = mask[gtid] ? 1.f : 0.f;
    const float diag = q + rho + lam1 * D[(size_t)gtid * (HU + 1)] + lam2 * sdiag;
    const float bb = rho * (L_in[gtid] - thP[gtid]) + (mask[gtid] ? x_in[gtid] : 0.f);
    const float di = 1.f / diag;
    ws[WS_DINV + gtid] = di;
    ws[WS_R0 + gtid] = bb;
    ws[WS_U0 + gtid] = bb * di;
  }

  // ---- stage this block's 16 D rows into LDS as fp16 (one-time 64 MB read) ----
  {
    const float4* __restrict__ Dg = (const float4*)(D + (size_t)b * 16 * HU);
    half4v* __restrict__ Dh4 = (half4v*)pool;
    for (int o = tid; o < 16 * HU / 4; o += NTHR) {
      const float4 dv = Dg[o];
      half4v h;
      h[0] = (_Float16)dv.x; h[1] = (_Float16)dv.y;
      h[2] = (_Float16)dv.z; h[3] = (_Float16)dv.w;
      Dh4[o] = h;
    }
  }
  if (tid < 8) red[tid] = 0.f;           // init barrier carries no delta
  gsync_dk(slots, flgq, ++gen, red, dks);

  // ---- every block mirrors r0,u0,dinv; r/s/dinv are thread-private -> regs ----
  float r_reg[8], s_reg[8], dinv_reg[8];
  float acc0 = 0.f;
#pragma unroll
  for (int m = 0; m < 8; ++m) {
    const int i = tid + m * NTHR;
    const float rv = ws[WS_R0 + i], uv = ws[WS_U0 + i];
    r_reg[m] = rv; u_l[i] = uv; dinv_reg[m] = ws[WS_DINV + i];
    s_reg[m] = 0.f;
  }
  __syncthreads();                       // u_l visible block-wide
#pragma unroll
  for (int m = 0; m < 8; ++m) acc0 = fmaf(r_reg[m], u_l[tid + m * NTHR], acc0);
  const float gamma0 = blockSum(acc0, red);

  // x/p state only matters on block 0 (SVT consumes x from its registers)
  float p_arr[8], x_arr[8];
#pragma unroll
  for (int m = 0; m < 8; ++m) { p_arr[m] = 0.f; x_arr[m] = 0.f; }

  const int row0 = b * 16 + wv * 2;      // 2 rows per wave
  const int iq = row0 >> 6, j0 = row0 & 63;
  const float4* __restrict__ u4 = (const float4*)u_l;
  const float m0 = mask[row0] ? 1.f : 0.f;
  const float m1 = mask[row0 + 1] ? 1.f : 0.f;
  const float sts0 = sts[j0 * 64 + lane];
  const float sts1 = sts[j0 * 64 + 64 + lane];
  // exact-diagonal correction: fp16(D_ii) error folded back in fp32
  const float dex0 = D[(size_t)row0 * (HU + 1)];
  const float dex1 = D[(size_t)(row0 + 1) * (HU + 1)];
  const float diagf0 = m0 + rho + lam1 * (dex0 - (float)(_Float16)dex0);
  const float diagf1 = m1 + rho + lam1 * (dex1 - (float)(_Float16)dex1);
  const half4v* __restrict__ H0 = (const half4v*)((_Float16*)pool + (size_t)(wv * 2) * HU);
  const half4v* __restrict__ H1 = H0 + (HU / 4);

  float gamma = gamma0, gamma_prev = 1.f, alpha_prev = 1.f;
  for (int k = 0; k < MAXIT; ++k) {
    // ---- matvec: w = A u (u + fp16 D both from LDS) ----
    float* __restrict__ wbuf = ws + WS_W + (k & 1) * HU;
    {
      float acc_a = 0.f, acc_b = 0.f;
#pragma unroll
      for (int it = 0; it < 16; ++it) {
        const float4 uu = u4[it * 64 + lane];
        const half4v d0 = H0[it * 64 + lane];
        const half4v d1 = H1[it * 64 + lane];
        acc_a = fmaf((float)d0[0], uu.x, acc_a); acc_a = fmaf((float)d0[1], uu.y, acc_a);
        acc_a = fmaf((float)d0[2], uu.z, acc_a); acc_a = fmaf((float)d0[3], uu.w, acc_a);
        acc_b = fmaf((float)d1[0], uu.x, acc_b); acc_b = fmaf((float)d1[1], uu.y, acc_b);
        acc_b = fmaf((float)d1[2], uu.z, acc_b); acc_b = fmaf((float)d1[3], uu.w, acc_b);
      }
      const float us = u_l[iq * 64 + lane];
      float t0 = fmaf(lam1, acc_a, lam2 * (sts0 * us));
      float t1 = fmaf(lam1, acc_b, lam2 * (sts1 * us));
      t0 = waveReduce(t0);
      t1 = waveReduce(t1);
      const float u0v = u_l[row0], u1v = u_l[row0 + 1];
      const float w0 = t0 + diagf0 * u0v;
      const float w1 = t1 + diagf1 * u1v;
      if (lane == 0) {
        wbuf[row0] = w0;
        wbuf[row0 + 1] = w1;
        red[wv] = fmaf(w0, u0v, w1 * u1v);   // this block's delta partial
      }
    }
    // ---- master-poll barrier; dk piggybacked on the release flag ----
    const float dk = gsync_dk(slots, flgq, ++gen, red, dks);

    // stage wbuf reads early (independent of the scalar math below)
    float wv_r[8];
#pragma unroll
    for (int m = 0; m < 8; ++m) wv_r[m] = wbuf[tid + m * NTHR];

    // ---- scalars (identical in every block: dk broadcast from master) ----
    const float beta  = (k == 0) ? 0.f : gamma * fastrcp(gamma_prev);
    const float denom = (k == 0) ? dk  : (dk - beta * gamma * fastrcp(alpha_prev));
    const float alpha = gamma * fastrcp(denom);

    // ---- redundant local update (p/x use uold = u_k read BEFORE overwrite) ----
    float acc = 0.f;
#pragma unroll
    for (int m = 0; m < 8; ++m) {
      const int i = tid + m * NTHR;
      const float uold = u_l[i];                       // u_k
      const float sv = (k == 0) ? wv_r[m] : fmaf(beta, s_reg[m], wv_r[m]);
      s_reg[m] = sv;
      const float rv = fmaf(-alpha, sv, r_reg[m]);
      r_reg[m] = rv;
      const float uv = rv * dinv_reg[m];               // u_{k+1}
      u_l[i] = uv;
      acc = fmaf(rv, uv, acc);
      if (b == 0) {                                    // only block 0 needs x
        const float pk = (k == 0) ? uold : fmaf(beta, p_arr[m], uold);
        p_arr[m] = pk;
        x_arr[m] = fmaf(alpha, pk, x_arr[m]);
      }
    }
    const float gnext = blockSum(acc, red);  // barrier also publishes u_l

    gamma_prev = gamma;
    alpha_prev = alpha;
    gamma = gnext;
    if (!(gnext > TOL2 * gamma0)) break; // uniform grid-wide (identical local math)
  }

  if (b != 0) return;                    // SVT runs on block 0 only; x in regs

  // =========================================================================
  // SVT: one-sided V-less Jacobi on Y = X + th_P.  Ltmp = W diag(g/s^2) W^T Y.
  // AG(2,8): 9 meta-rounds/sweep (unrolled: gf8mul folds), 7-round in-octet
  // tournament barrier-free. NORM-CARRYING: nrm[c] holds ||W col c||^2.
  // =========================================================================
  float* Wl = (float*)pool;              // W col-major: Wl[c*S_W + r]
  float* Yr = Wl + 64 * S_W;             // pristine Y ROW-major
  float* T1 = Yr + 64 * S_W;             // T1[k][j] = (W^T Y)[k][j]
  float* Wr = T1 + 64 * S_W;             // Wr[i][k] = W[i][k]*gg[k]
  __syncthreads();

  float t0acc = 0.f;
#pragma unroll
  for (int mm = 0; mm < 8; ++mm) {
    const int i = tid + mm * NTHR;
    const int rr = i >> 6, cc = i & 63;
    const float y = x_arr[mm] + thP[i];
    Wl[cc * S_W + rr] = y;
    Yr[rr * S_W + cc] = y;
    t0acc = fmaf(y, y, t0acc);
  }
  const float T0 = blockSum(t0acc, red);     // barrier: Wl now visible
  // initial column norms
  if (tid < 64) {
    const float4* wc = (const float4*)(Wl + tid * S_W);
    float nn = 0.f;
#pragma unroll
    for (int i2 = 0; i2 < 16; ++i2) {
      const float4 u = wc[i2];
      nn = fmaf(u.x, u.x, fmaf(u.y, u.y, fmaf(u.z, u.z, fmaf(u.w, u.w, nn))));
    }
    nrm[tid] = nn;
  }
  __syncthreads();
  // exit when true off_F^2 <= 1e-11*T0^2 (offacc is x16: every lane counts)
  const float thr = 1.6e-10f * T0 * T0;

  const int team = lane >> 4;                // pair-team within wave, 0..3
  const int sub  = lane & 15;                // slice within column (4 floats)

  for (int sweep = 0; sweep < SWP; ++sweep) {
    float offacc = 0.f;
#pragma unroll
    for (int mr = 0; mr < 9; ++mr) {
      // this wave's octet: line wv of parallel class mr in AG(2,8)
      int cols[8];
#pragma unroll
      for (int j = 0; j < 8; ++j)
        cols[j] = (mr == 8) ? (8 * wv + j) : (8 * j + (gf8mul(mr, j) ^ wv));
      // 7-round tournament inside the octet — no block barrier
      for (int r = 0; r < 7; ++r) {
        const int pi = (team == 0) ? 7 : ((r + team) % 7);
        const int qi = (team == 0) ? (r % 7) : ((r + 7 - team) % 7);
        const int cp = sel8(cols, pi);
        const int cq = sel8(cols, qi);
        float4* wp = (float4*)(Wl + cp * S_W) + sub;
        float4* wq = (float4*)(Wl + cq * S_W) + sub;
        const float4 a = *wp, bb = *wq;
        const float dpp = nrm[cp];             // carried (LDS broadcast)
        const float dqq = nrm[cq];
        float dpq = fmaf(a.x, bb.x, fmaf(a.y, bb.y, fmaf(a.z, bb.z, a.w * bb.w)));
        dpq = red16(dpq);                      // the ONLY reduce per round
        offacc = fmaf(dpq, dpq, offacc);
        // team-uniform skip of converged pairs
        if (dpq * dpq > 1e-14f * dpp * dqq) {
          // 3-transcendental rotation params (chain: rsq -> sqrt -> rcp):
          // h = sqrt(d^2 + (2dpq)^2); c = sqrt((1+|d|/h)/2);
          // s = sign(d) * dpq/(h*c)   — algebraically identical to the
          // classic smaller-angle Jacobi rotation (verified).
          const float d  = dqq - dpp;
          const float u2 = 2.f * dpq;
          const float z  = fmaf(d, d, u2 * u2);
          const float ih = fastrsq(z);
          const float c1 = fastsqrt(fmaf(0.5f * fabsf(d), ih, 0.5f));
          const float sg = (d >= 0.f) ? 0.5f : -0.5f;
          const float s1 = sg * u2 * ih * fastrcp(c1);
          float4 na, nb;
          na.x = c1 * a.x - s1 * bb.x;  nb.x = s1 * a.x + c1 * bb.x;
          na.y = c1 * a.y - s1 * bb.y;  nb.y = s1 * a.y + c1 * bb.y;
          na.z = c1 * a.z - s1 * bb.z;  nb.z = s1 * a.z + c1 * bb.z;
          na.w = c1 * a.w - s1 * bb.w;  nb.w = s1 * a.w + c1 * bb.w;
          *wp = na; *wq = nb;
          if (sub == 0) {                      // analytic norm update
            const float cc2 = c1 * c1, ss2 = s1 * s1, cs2 = 2.f * c1 * s1;
            nrm[cp] = cc2 * dpp - cs2 * dpq + ss2 * dqq;
            nrm[cq] = ss2 * dpp + cs2 * dpq + cc2 * dqq;
          }
        }
      }
      __syncthreads();                   // octet handoff between meta-rounds
    }
    // certificate on PRE-sweep state; post-sweep off is quadratically smaller.
    const float tot = blockSum(offacc, red);
    if (tot < thr) break;
  }

  // ---- sigma from column norms (FRESH, not carried); gg = relu(s-tau)/s^3 ----
  if (tid < 64) {
    const float4* wc = (const float4*)(Wl + tid * S_W);
    float nn = 0.f;
#pragma unroll
    for (int i2 = 0; i2 < 16; ++i2) {
      const float4 u = wc[i2];
      nn = fmaf(u.x, u.x, fmaf(u.y, u.y, fmaf(u.z, u.z, fmaf(u.w, u.w, nn))));
    }
    const float sv = sqrtf(nn);
    const float tau = (*cgp) / (1.f + expf(-(*vp)));
    g_s[tid] = (sv > tau) ? (sv - tau) / (sv * nn) : 0.f;   // (s-tau)/s^3
  }
  __syncthreads();

  const int j = tid & 63;
  const int ib = tid >> 6;

  // ---- T1[k][j] = sum_i W[i][k] * Y[i][j] ----
#pragma unroll
  for (int mm = 0; mm < 8; ++mm) {
    const int k = ib + 8 * mm;                        // uniform per wave
    const float4* wcol = (const float4*)(Wl + k * S_W);
    float acc = 0.f;
#pragma unroll
    for (int i4 = 0; i4 < 16; ++i4) {
      const float4 wvv = wcol[i4];                    // LDS broadcast
      acc = fmaf(wvv.x, Yr[(4 * i4 + 0) * S_W + j], acc);
      acc = fmaf(wvv.y, Yr[(4 * i4 + 1) * S_W + j], acc);
      acc = fmaf(wvv.z, Yr[(4 * i4 + 2) * S_W + j], acc);
      acc = fmaf(wvv.w, Yr[(4 * i4 + 3) * S_W + j], acc);
    }
    T1[k * S_W + j] = acc;
  }
  // ---- Wr[i][k] = W[i][k] * gg[k] (transpose with gain fold) ----
  for (int o = tid; o < 4096; o += 512) {
    const int i2 = o >> 6, kk = o & 63;
    Wr[i2 * S_W + kk] = Wl[kk * S_W + i2] * g_s[kk];
  }
  __syncthreads();

  // ---- Ltmp = Wr * T1; Ptmp = thP + neta (X - Ltmp)  (X from registers) ----
  const float neta = *netap;
#pragma unroll
  for (int mm = 0; mm < 8; ++mm) {
    const int i2 = ib + 8 * mm;                       // uniform per wave
    const float4* wrow = (const float4*)(Wr + i2 * S_W);
    float acc = 0.f;
#pragma unroll
    for (int k4 = 0; k4 < 16; ++k4) {
      const float4 wvv = wrow[k4];                    // LDS broadcast
      acc = fmaf(wvv.x, T1[(4 * k4 + 0) * S_W + j], acc);
      acc = fmaf(wvv.y, T1[(4 * k4 + 1) * S_W + j], acc);
      acc = fmaf(wvv.z, T1[(4 * k4 + 2) * S_W + j], acc);
      acc = fmaf(wvv.w, T1[(4 * k4 + 3) * S_W + j], acc);
    }
    const int o = i2 * 64 + j;                        // == tid + mm*512
    out[o] = acc;                                     // Ltmp
    out[4096 + o] = thP[o] + neta * (x_arr[mm] - acc);// Ptmp
  }
}

extern "C" void kernel_launch(void* const* d_in, const int* in_sizes, int n_in,
                              void* d_out, int out_size, void* d_ws, size_t ws_size,
                              hipStream_t stream)
{
  const float* x_in  = (const float*)d_in[0];
  const float* L_in  = (const float*)d_in[1];
  const int*   mask  = (const int*)d_in[2];
  const float* D     = (const float*)d_in[3];
  const float* thP   = (const float*)d_in[4];
  const float* vp    = (const float*)d_in[5];
  const float* cgp   = (const float*)d_in[6];
  const float* netap = (const float*)d_in[7];
  const float* l1p   = (const float*)d_in[8];
  const float* l2p   = (const float*)d_in[9];
  const float* rhop  = (const float*)d_in[10];
  const float* S     = (const float*)d_in[11];
  float* ws  = (float*)d_ws;
  float* out = (float*)d_out;

  // zero the tagged slots + flag lines (re-runs on every graph replay)
  hipMemsetAsync(ws + WS_BAR, 0, (WS_END - WS_BAR) * sizeof(float), stream);

  void* args[] = { (void*)&x_in, (void*)&L_in, (void*)&mask, (void*)&D, (void*)&thP,
                   (void*)&S, (void*)&l1p, (void*)&l2p, (void*)&rhop,
                   (void*)&vp, (void*)&cgp, (void*)&netap, (void*)&ws, (void*)&out };
  hipLaunchCooperativeKernel((void*)fused_kernel, dim3(NBLK), dim3(NTHR),
                             args, 0, stream);
}

// Round 12
// 316.034 us; speedup vs baseline: 1.0576x; 1.0000x over previous
//
#include <hip/hip_runtime.h>
#include <cstddef>

#define HU    4096
#define NBLK  256
#define NTHR  512
#define MAXIT 100
#define TOL2  1e-7f

// workspace layout (float offsets)
#define WS_STS  0
#define WS_DINV 4096
#define WS_R0   8192
#define WS_U0   12288
#define WS_W    16384                    // DOUBLE buffer: 2 x 4096 (parity k&1)
#define WS_BAR  24576                    // 2 x 256 tagged 8B slots (parity gen&1)
#define WS_FLG  (WS_BAR + 1024)          // 8 x 64B flag lines: (gen<<32)|dk bits
#define WS_END  (WS_FLG + 128)

typedef _Float16 half4v __attribute__((ext_vector_type(4)));

// raw-approx transcendentals — avoids hipcc's IEEE div/sqrt expansion on the
// Jacobi critical path. c^2+s^2 = 1 +- 3e-7 per rotation: drift ~1e-4, safe.
__device__ __forceinline__ float fastrcp(float x) {
  float r; asm("v_rcp_f32 %0, %1" : "=v"(r) : "v"(x)); return r;
}
__device__ __forceinline__ float fastsqrt(float x) {
  float r; asm("v_sqrt_f32 %0, %1" : "=v"(r) : "v"(x)); return r;
}
__device__ __forceinline__ float fastrsq(float x) {
  float r; asm("v_rsq_f32 %0, %1" : "=v"(r) : "v"(x)); return r;
}

__device__ __forceinline__ float waveReduce(float v) {
#pragma unroll
  for (int off = 32; off > 0; off >>= 1) v += __shfl_xor(v, off, 64);
  return v;
}

// Block-wide sum over 8 waves; returns same value in all threads.
__device__ __forceinline__ float blockSum(float v, float* red) {
  v = waveReduce(v);
  if ((threadIdx.x & 63) == 0) red[threadIdx.x >> 6] = v;
  __syncthreads();
  float s = 0.f;
#pragma unroll
  for (int i = 0; i < 8; ++i) s += red[i];
  __syncthreads();
  return s;
}

// ---------------------------------------------------------------------------
// Grid barrier + global dot-product, master-poll topology:
//  - every block release-stores (gen<<32 | bits(block_delta)) into its own
//    tagged 8B slot (parity gen&1; no atomic RMW anywhere);
//  - ONLY block 0's wave 0 polls the 256 slots (4 loads/lane); on success the
//    registers already hold all deltas -> dk = waveReduce, no extra gather;
//  - release fans out to 8 XCD-spread flag lines carrying (gen<<32 | dk bits);
//    spinners read ONE 8B word to get both barrier release and dk.
// Master poll is UN-slept: it no longer contends with spinners (they watch
// flgq), and s_sleep only quantized the release path. Spinner sleeps stay.
// dk returns via a DEDICATED LDS slot (dks): no trailing guard barrier
// (next write to dks is ordered by the next call's entry __syncthreads()).
// ---------------------------------------------------------------------------
__device__ __forceinline__ float gsync_dk(unsigned long long* slots,
                                          unsigned long long* flgq,
                                          unsigned gen, float* red, float* dks) {
  __syncthreads();                       // red[] complete + block's global writes done
  const int tid = threadIdx.x, lane = tid & 63, b = blockIdx.x;
  unsigned long long* arr = slots + (gen & 1) * 256;
  if (b == 0) {
    if (tid < 64) {
      if (lane == 0) {
        float s = 0.f;
#pragma unroll
        for (int i = 0; i < 8; ++i) s += red[i];
        __threadfence();                 // release all prior global writes
        __hip_atomic_store(&arr[0],
                           ((unsigned long long)gen << 32) | __float_as_uint(s),
                           __ATOMIC_RELEASE, __HIP_MEMORY_SCOPE_AGENT);
      }
      float dsum;
      for (;;) {
        const unsigned long long v0 = __hip_atomic_load(&arr[lane],
                                        __ATOMIC_RELAXED, __HIP_MEMORY_SCOPE_AGENT);
        const unsigned long long v1 = __hip_atomic_load(&arr[lane + 64],
                                        __ATOMIC_RELAXED, __HIP_MEMORY_SCOPE_AGENT);
        const unsigned long long v2 = __hip_atomic_load(&arr[lane + 128],
                                        __ATOMIC_RELAXED, __HIP_MEMORY_SCOPE_AGENT);
        const unsigned long long v3 = __hip_atomic_load(&arr[lane + 192],
                                        __ATOMIC_RELAXED, __HIP_MEMORY_SCOPE_AGENT);
        const bool ok = ((unsigned)(v0 >> 32) >= gen) && ((unsigned)(v1 >> 32) >= gen)
                     && ((unsigned)(v2 >> 32) >= gen) && ((unsigned)(v3 >> 32) >= gen);
        if (__all(ok)) {
          dsum = __uint_as_float((unsigned)v0) + __uint_as_float((unsigned)v1)
               + __uint_as_float((unsigned)v2) + __uint_as_float((unsigned)v3);
          break;
        }
        // no s_sleep: poll period is already bounded by the 4 load latencies
      }
      const float dk = waveReduce(dsum);
      __threadfence();                   // acquire: see all blocks' writes
      if (lane < 8)
        __hip_atomic_store(&flgq[lane * 8],
                           ((unsigned long long)gen << 32) | __float_as_uint(dk),
                           __ATOMIC_RELEASE, __HIP_MEMORY_SCOPE_AGENT);
      if (lane == 0) dks[0] = dk;
    }
  } else if (tid == 0) {
    float s = 0.f;
#pragma unroll
    for (int i = 0; i < 8; ++i) s += red[i];
    __threadfence();                     // release all prior global writes
    __hip_atomic_store(&arr[b],
                       ((unsigned long long)gen << 32) | __float_as_uint(s),
                       __ATOMIC_RELEASE, __HIP_MEMORY_SCOPE_AGENT);
    unsigned long long* fq = flgq + (b & 7) * 8;
    unsigned long long f;
    for (;;) {
      f = __hip_atomic_load(fq, __ATOMIC_RELAXED, __HIP_MEMORY_SCOPE_AGENT);
      if ((unsigned)(f >> 32) >= gen) break;
      __builtin_amdgcn_s_sleep(1);
    }
    __threadfence();                     // acquire: see all blocks' writes
    dks[0] = __uint_as_float((unsigned)f);
  }
  __syncthreads();
  return dks[0];                         // no guard needed: next write to dks
                                         // is after the next call's entry sync
}

#define SWP 6          // max Jacobi sweeps
#define S_W 68         // column stride in floats (16B-aligned, bank-spreading)

// sum across each 16-lane group via DPP row_ror (VALU pipe, not LDS unit)
__device__ __forceinline__ float red16(float x) {
  int t;
  t = __builtin_amdgcn_update_dpp(0, __float_as_int(x), 0x128, 0xF, 0xF, false); // row_ror:8
  x += __int_as_float(t);
  t = __builtin_amdgcn_update_dpp(0, __float_as_int(x), 0x124, 0xF, 0xF, false); // row_ror:4
  x += __int_as_float(t);
  t = __builtin_amdgcn_update_dpp(0, __float_as_int(x), 0x122, 0xF, 0xF, false); // row_ror:2
  x += __int_as_float(t);
  t = __builtin_amdgcn_update_dpp(0, __float_as_int(x), 0x121, 0xF, 0xF, false); // row_ror:1
  x += __int_as_float(t);
  return x;
}

// GF(8) multiply, poly x^3 + x + 1
__device__ __forceinline__ int gf8mul(int a, int b) {
  int p = 0;
  if (b & 1) p ^= a;
  if (b & 2) p ^= (a << 1);
  if (b & 4) p ^= (a << 2);
  if (p & 16) p ^= 22;                   // x^4 -> x^2 + x
  if (p & 8)  p ^= 11;                   // x^3 -> x + 1
  return p;
}

// runtime-index select from an 8-entry register array (cndmask chain, no scratch)
__device__ __forceinline__ int sel8(const int c[8], int i) {
  int r = c[0];
  r = (i == 1) ? c[1] : r;
  r = (i == 2) ? c[2] : r;
  r = (i == 3) ? c[3] : r;
  r = (i == 4) ? c[4] : r;
  r = (i == 5) ? c[5] : r;
  r = (i == 6) ? c[6] : r;
  r = (i == 7) ? c[7] : r;
  return r;
}

// ---------------------------------------------------------------------------
// FUSED kernel: CG solve (all 256 blocks, cooperative) then SVT (block 0 only,
// one-sided V-less Jacobi, AG(2,8) schedule — mr loop UNROLLED so gf8mul
// constant-folds — norm-carrying inner loop, 3-transcendental rotation params.
// ---------------------------------------------------------------------------
__global__ void __launch_bounds__(NTHR, 1)
fused_kernel(const float* __restrict__ x_in, const float* __restrict__ L_in,
             const int* __restrict__ mask, const float* __restrict__ D,
             const float* __restrict__ thP, const float* __restrict__ S,
             const float* __restrict__ l1p, const float* __restrict__ l2p,
             const float* __restrict__ rhop, const float* __restrict__ vp,
             const float* __restrict__ cgp, const float* __restrict__ netap,
             float* __restrict__ ws, float* __restrict__ out)
{
  __shared__ __align__(16) float u_l[HU];          // 16 KB (block-shared u)
  __shared__ __align__(16) char pool[128 * 1024];  // CG: fp16 D rows | SVT: Wl/Yr/T1/Wr
  __shared__ float red[8];
  __shared__ float dks[1];                         // dk broadcast slot
  __shared__ float g_s[64];
  __shared__ float nrm[64];                        // carried column norms (SVT)
  unsigned long long* slots = (unsigned long long*)(ws + WS_BAR);
  unsigned long long* flgq  = (unsigned long long*)(ws + WS_FLG);
  const float* sts = ws + WS_STS;
  const float lam1 = *l1p, lam2 = *l2p, rho = *rhop;
  const int tid = threadIdx.x, b = blockIdx.x;
  const int wv = tid >> 6, lane = tid & 63;
  unsigned gen = 0;

  // ---- init (blocks 0..7 write global sts/dinv/r0/u0) ----
  const int gtid = b * NTHR + tid;
  if (gtid < HU) {
    const int a = gtid >> 6, c = gtid & 63;
    float acc = 0.f, sdiag = 0.f;
    for (int h = 0; h < 64; ++h) {
      const float sa = S[h * 64 + a], sc = S[h * 64 + c];
      acc = fmaf(sa, sc, acc);
      sdiag = fmaf(sc, sc, sdiag);
    }
    ws[WS_STS + gtid] = acc;
    const float q = mask[gtid] ? 1.f : 0.f;
    const float diag = q + rho + lam1 * D[(size_t)gtid * (HU + 1)] + lam2 * sdiag;
    const float bb = rho * (L_in[gtid] - thP[gtid]) + (mask[gtid] ? x_in[gtid] : 0.f);
    const float di = 1.f / diag;
    ws[WS_DINV + gtid] = di;
    ws[WS_R0 + gtid] = bb;
    ws[WS_U0 + gtid] = bb * di;
  }

  // ---- stage this block's 16 D rows into LDS as fp16 (one-time 64 MB read) ----
  {
    const float4* __restrict__ Dg = (const float4*)(D + (size_t)b * 16 * HU);
    half4v* __restrict__ Dh4 = (half4v*)pool;
    for (int o = tid; o < 16 * HU / 4; o += NTHR) {
      const float4 dv = Dg[o];
      half4v h;
      h[0] = (_Float16)dv.x; h[1] = (_Float16)dv.y;
      h[2] = (_Float16)dv.z; h[3] = (_Float16)dv.w;
      Dh4[o] = h;
    }
  }
  if (tid < 8) red[tid] = 0.f;           // init barrier carries no delta
  gsync_dk(slots, flgq, ++gen, red, dks);

  // ---- every block mirrors r0,u0,dinv; r/s/dinv are thread-private -> regs ----
  float r_reg[8], s_reg[8], dinv_reg[8];
  float acc0 = 0.f;
#pragma unroll
  for (int m = 0; m < 8; ++m) {
    const int i = tid + m * NTHR;
    const float rv = ws[WS_R0 + i], uv = ws[WS_U0 + i];
    r_reg[m] = rv; u_l[i] = uv; dinv_reg[m] = ws[WS_DINV + i];
    s_reg[m] = 0.f;
  }
  __syncthreads();                       // u_l visible block-wide
#pragma unroll
  for (int m = 0; m < 8; ++m) acc0 = fmaf(r_reg[m], u_l[tid + m * NTHR], acc0);
  const float gamma0 = blockSum(acc0, red);

  // x/p state only matters on block 0 (SVT consumes x from its registers)
  float p_arr[8], x_arr[8];
#pragma unroll
  for (int m = 0; m < 8; ++m) { p_arr[m] = 0.f; x_arr[m] = 0.f; }

  const int row0 = b * 16 + wv * 2;      // 2 rows per wave
  const int iq = row0 >> 6, j0 = row0 & 63;
  const float4* __restrict__ u4 = (const float4*)u_l;
  const float m0 = mask[row0] ? 1.f : 0.f;
  const float m1 = mask[row0 + 1] ? 1.f : 0.f;
  const float sts0 = sts[j0 * 64 + lane];
  const float sts1 = sts[j0 * 64 + 64 + lane];
  // exact-diagonal correction: fp16(D_ii) error folded back in fp32
  const float dex0 = D[(size_t)row0 * (HU + 1)];
  const float dex1 = D[(size_t)(row0 + 1) * (HU + 1)];
  const float diagf0 = m0 + rho + lam1 * (dex0 - (float)(_Float16)dex0);
  const float diagf1 = m1 + rho + lam1 * (dex1 - (float)(_Float16)dex1);
  const half4v* __restrict__ H0 = (const half4v*)((_Float16*)pool + (size_t)(wv * 2) * HU);
  const half4v* __restrict__ H1 = H0 + (HU / 4);

  float gamma = gamma0, gamma_prev = 1.f, alpha_prev = 1.f;
  for (int k = 0; k < MAXIT; ++k) {
    // ---- matvec: w = A u (u + fp16 D both from LDS) ----
    float* __restrict__ wbuf = ws + WS_W + (k & 1) * HU;
    {
      float acc_a = 0.f, acc_b = 0.f;
#pragma unroll
      for (int it = 0; it < 16; ++it) {
        const float4 uu = u4[it * 64 + lane];
        const half4v d0 = H0[it * 64 + lane];
        const half4v d1 = H1[it * 64 + lane];
        acc_a = fmaf((float)d0[0], uu.x, acc_a); acc_a = fmaf((float)d0[1], uu.y, acc_a);
        acc_a = fmaf((float)d0[2], uu.z, acc_a); acc_a = fmaf((float)d0[3], uu.w, acc_a);
        acc_b = fmaf((float)d1[0], uu.x, acc_b); acc_b = fmaf((float)d1[1], uu.y, acc_b);
        acc_b = fmaf((float)d1[2], uu.z, acc_b); acc_b = fmaf((float)d1[3], uu.w, acc_b);
      }
      const float us = u_l[iq * 64 + lane];
      float t0 = fmaf(lam1, acc_a, lam2 * (sts0 * us));
      float t1 = fmaf(lam1, acc_b, lam2 * (sts1 * us));
      t0 = waveReduce(t0);
      t1 = waveReduce(t1);
      const float u0v = u_l[row0], u1v = u_l[row0 + 1];
      const float w0 = t0 + diagf0 * u0v;
      const float w1 = t1 + diagf1 * u1v;
      if (lane == 0) {
        wbuf[row0] = w0;
        wbuf[row0 + 1] = w1;
        red[wv] = fmaf(w0, u0v, w1 * u1v);   // this block's delta partial
      }
    }
    // ---- master-poll barrier; dk piggybacked on the release flag ----
    const float dk = gsync_dk(slots, flgq, ++gen, red, dks);

    // stage wbuf reads early (independent of the scalar math below)
    float wv_r[8];
#pragma unroll
    for (int m = 0; m < 8; ++m) wv_r[m] = wbuf[tid + m * NTHR];

    // ---- scalars (identical in every block: dk broadcast from master) ----
    const float beta  = (k == 0) ? 0.f : gamma * fastrcp(gamma_prev);
    const float denom = (k == 0) ? dk  : (dk - beta * gamma * fastrcp(alpha_prev));
    const float alpha = gamma * fastrcp(denom);

    // ---- redundant local update (p/x use uold = u_k read BEFORE overwrite) ----
    float acc = 0.f;
#pragma unroll
    for (int m = 0; m < 8; ++m) {
      const int i = tid + m * NTHR;
      const float uold = u_l[i];                       // u_k
      const float sv = (k == 0) ? wv_r[m] : fmaf(beta, s_reg[m], wv_r[m]);
      s_reg[m] = sv;
      const float rv = fmaf(-alpha, sv, r_reg[m]);
      r_reg[m] = rv;
      const float uv = rv * dinv_reg[m];               // u_{k+1}
      u_l[i] = uv;
      acc = fmaf(rv, uv, acc);
      if (b == 0) {                                    // only block 0 needs x
        const float pk = (k == 0) ? uold : fmaf(beta, p_arr[m], uold);
        p_arr[m] = pk;
        x_arr[m] = fmaf(alpha, pk, x_arr[m]);
      }
    }
    const float gnext = blockSum(acc, red);  // barrier also publishes u_l

    gamma_prev = gamma;
    alpha_prev = alpha;
    gamma = gnext;
    if (!(gnext > TOL2 * gamma0)) break; // uniform grid-wide (identical local math)
  }

  if (b != 0) return;                    // SVT runs on block 0 only; x in regs

  // =========================================================================
  // SVT: one-sided V-less Jacobi on Y = X + th_P.  Ltmp = W diag(g/s^2) W^T Y.
  // AG(2,8): 9 meta-rounds/sweep (unrolled: gf8mul folds), 7-round in-octet
  // tournament barrier-free. NORM-CARRYING: nrm[c] holds ||W col c||^2.
  // =========================================================================
  float* Wl = (float*)pool;              // W col-major: Wl[c*S_W + r]
  float* Yr = Wl + 64 * S_W;             // pristine Y ROW-major
  float* T1 = Yr + 64 * S_W;             // T1[k][j] = (W^T Y)[k][j]
  float* Wr = T1 + 64 * S_W;             // Wr[i][k] = W[i][k]*gg[k]
  __syncthreads();

  float t0acc = 0.f;
#pragma unroll
  for (int mm = 0; mm < 8; ++mm) {
    const int i = tid + mm * NTHR;
    const int rr = i >> 6, cc = i & 63;
    const float y = x_arr[mm] + thP[i];
    Wl[cc * S_W + rr] = y;
    Yr[rr * S_W + cc] = y;
    t0acc = fmaf(y, y, t0acc);
  }
  const float T0 = blockSum(t0acc, red);     // barrier: Wl now visible
  // initial column norms
  if (tid < 64) {
    const float4* wc = (const float4*)(Wl + tid * S_W);
    float nn = 0.f;
#pragma unroll
    for (int i2 = 0; i2 < 16; ++i2) {
      const float4 u = wc[i2];
      nn = fmaf(u.x, u.x, fmaf(u.y, u.y, fmaf(u.z, u.z, fmaf(u.w, u.w, nn))));
    }
    nrm[tid] = nn;
  }
  __syncthreads();
  // LOOSENED certificate: exit when true off_F^2 <= 1e-8*T0^2 (offacc is x16).
  // Exit happens AFTER the sweep that measured it; quadratic contraction
  // leaves post-exit off ~1e-7*T0. V-less reconstruction error is bounded by
  // off_post/tau^2-scale terms (sigma<tau columns get gain 0), ~1e-6 abs —
  // 3 orders below the measured 2^-7 output floor (stable for 12 rounds).
  const float thr = 1.6e-7f * T0 * T0;

  const int team = lane >> 4;                // pair-team within wave, 0..3
  const int sub  = lane & 15;                // slice within column (4 floats)

  for (int sweep = 0; sweep < SWP; ++sweep) {
    float offacc = 0.f;
#pragma unroll
    for (int mr = 0; mr < 9; ++mr) {
      // this wave's octet: line wv of parallel class mr in AG(2,8)
      int cols[8];
#pragma unroll
      for (int j = 0; j < 8; ++j)
        cols[j] = (mr == 8) ? (8 * wv + j) : (8 * j + (gf8mul(mr, j) ^ wv));
      // 7-round tournament inside the octet — no block barrier
      for (int r = 0; r < 7; ++r) {
        const int pi = (team == 0) ? 7 : ((r + team) % 7);
        const int qi = (team == 0) ? (r % 7) : ((r + 7 - team) % 7);
        const int cp = sel8(cols, pi);
        const int cq = sel8(cols, qi);
        float4* wp = (float4*)(Wl + cp * S_W) + sub;
        float4* wq = (float4*)(Wl + cq * S_W) + sub;
        const float4 a = *wp, bb = *wq;
        const float dpp = nrm[cp];             // carried (LDS broadcast)
        const float dqq = nrm[cq];
        float dpq = fmaf(a.x, bb.x, fmaf(a.y, bb.y, fmaf(a.z, bb.z, a.w * bb.w)));
        dpq = red16(dpq);                      // the ONLY reduce per round
        offacc = fmaf(dpq, dpq, offacc);
        // team-uniform skip of converged pairs
        if (dpq * dpq > 1e-14f * dpp * dqq) {
          // 3-transcendental rotation params (chain: rsq -> sqrt -> rcp):
          // h = sqrt(d^2 + (2dpq)^2); c = sqrt((1+|d|/h)/2);
          // s = sign(d) * dpq/(h*c)   — algebraically identical to the
          // classic smaller-angle Jacobi rotation.
          const float d  = dqq - dpp;
          const float u2 = 2.f * dpq;
          const float z  = fmaf(d, d, u2 * u2);
          const float ih = fastrsq(z);
          const float c1 = fastsqrt(fmaf(0.5f * fabsf(d), ih, 0.5f));
          const float sg = (d >= 0.f) ? 0.5f : -0.5f;
          const float s1 = sg * u2 * ih * fastrcp(c1);
          float4 na, nb;
          na.x = c1 * a.x - s1 * bb.x;  nb.x = s1 * a.x + c1 * bb.x;
          na.y = c1 * a.y - s1 * bb.y;  nb.y = s1 * a.y + c1 * bb.y;
          na.z = c1 * a.z - s1 * bb.z;  nb.z = s1 * a.z + c1 * bb.z;
          na.w = c1 * a.w - s1 * bb.w;  nb.w = s1 * a.w + c1 * bb.w;
          *wp = na; *wq = nb;
          if (sub == 0) {                      // analytic norm update
            const float cc2 = c1 * c1, ss2 = s1 * s1, cs2 = 2.f * c1 * s1;
            nrm[cp] = cc2 * dpp - cs2 * dpq + ss2 * dqq;
            nrm[cq] = ss2 * dpp + cs2 * dpq + cc2 * dqq;
          }
        }
      }
      __syncthreads();                   // octet handoff between meta-rounds
    }
    // certificate on PRE-sweep state; post-sweep off is quadratically smaller.
    const float tot = blockSum(offacc, red);
    if (tot < thr) break;
  }

  // ---- sigma from column norms (FRESH, not carried); gg = relu(s-tau)/s^3 ----
  if (tid < 64) {
    const float4* wc = (const float4*)(Wl + tid * S_W);
    float nn = 0.f;
#pragma unroll
    for (int i2 = 0; i2 < 16; ++i2) {
      const float4 u = wc[i2];
      nn = fmaf(u.x, u.x, fmaf(u.y, u.y, fmaf(u.z, u.z, fmaf(u.w, u.w, nn))));
    }
    const float sv = sqrtf(nn);
    const float tau = (*cgp) / (1.f + expf(-(*vp)));
    g_s[tid] = (sv > tau) ? (sv - tau) / (sv * nn) : 0.f;   // (s-tau)/s^3
  }
  __syncthreads();

  const int j = tid & 63;
  const int ib = tid >> 6;

  // ---- T1[k][j] = sum_i W[i][k] * Y[i][j] ----
#pragma unroll
  for (int mm = 0; mm < 8; ++mm) {
    const int k = ib + 8 * mm;                        // uniform per wave
    const float4* wcol = (const float4*)(Wl + k * S_W);
    float acc = 0.f;
#pragma unroll
    for (int i4 = 0; i4 < 16; ++i4) {
      const float4 wvv = wcol[i4];                    // LDS broadcast
      acc = fmaf(wvv.x, Yr[(4 * i4 + 0) * S_W + j], acc);
      acc = fmaf(wvv.y, Yr[(4 * i4 + 1) * S_W + j], acc);
      acc = fmaf(wvv.z, Yr[(4 * i4 + 2) * S_W + j], acc);
      acc = fmaf(wvv.w, Yr[(4 * i4 + 3) * S_W + j], acc);
    }
    T1[k * S_W + j] = acc;
  }
  // ---- Wr[i][k] = W[i][k] * gg[k] (transpose with gain fold) ----
  for (int o = tid; o < 4096; o += 512) {
    const int i2 = o >> 6, kk = o & 63;
    Wr[i2 * S_W + kk] = Wl[kk * S_W + i2] * g_s[kk];
  }
  __syncthreads();

  // ---- Ltmp = Wr * T1; Ptmp = thP + neta (X - Ltmp)  (X from registers) ----
  const float neta = *netap;
#pragma unroll
  for (int mm = 0; mm < 8; ++mm) {
    const int i2 = ib + 8 * mm;                       // uniform per wave
    const float4* wrow = (const float4*)(Wr + i2 * S_W);
    float acc = 0.f;
#pragma unroll
    for (int k4 = 0; k4 < 16; ++k4) {
      const float4 wvv = wrow[k4];                    // LDS broadcast
      acc = fmaf(wvv.x, T1[(4 * k4 + 0) * S_W + j], acc);
      acc = fmaf(wvv.y, T1[(4 * k4 + 1) * S_W + j], acc);
      acc = fmaf(wvv.z, T1[(4 * k4 + 2) * S_W + j], acc);
      acc = fmaf(wvv.w, T1[(4 * k4 + 3) * S_W + j], acc);
    }
    const int o = i2 * 64 + j;                        // == tid + mm*512
    out[o] = acc;                                     // Ltmp
    out[4096 + o] = thP[o] + neta * (x_arr[mm] - acc);// Ptmp
  }
}

extern "C" void kernel_launch(void* const* d_in, const int* in_sizes, int n_in,
                              void* d_out, int out_size, void* d_ws, size_t ws_size,
                              hipStream_t stream)
{
  const float* x_in  = (const float*)d_in[0];
  const float* L_in  = (const float*)d_in[1];
  const int*   mask  = (const int*)d_in[2];
  const float* D     = (const float*)d_in[3];
  const float* thP   = (const float*)d_in[4];
  const float* vp    = (const float*)d_in[5];
  const float* cgp   = (const float*)d_in[6];
  const float* netap = (const float*)d_in[7];
  const float* l1p   = (const float*)d_in[8];
  const float* l2p   = (const float*)d_in[9];
  const float* rhop  = (const float*)d_in[10];
  const float* S     = (const float*)d_in[11];
  float* ws  = (float*)d_ws;
  float* out = (float*)d_out;

  // zero the tagged slots + flag lines (re-runs on every graph replay)
  hipMemsetAsync(ws + WS_BAR, 0, (WS_END - WS_BAR) * sizeof(float), stream);

  void* args[] = { (void*)&x_in, (void*)&L_in, (void*)&mask, (void*)&D, (void*)&thP,
                   (void*)&S, (void*)&l1p, (void*)&l2p, (void*)&rhop,
                   (void*)&vp, (void*)&cgp, (void*)&netap, (void*)&ws, (void*)&out };
  hipLaunchCooperativeKernel((void*)fused_kernel, dim3(NBLK), dim3(NTHR),
                             args, 0, stream);
}